// Round 1
// baseline (158.127 us; speedup 1.0000x reference)
//
#include <hip/hip_runtime.h>
#include <float.h>
#include <math.h>

#define CCH 256       // channels
#define PIX 4096      // 64*64 feature pixels
#define LREF 64       // number of reference feats
#define NGRID 16      // grids per side
#define IMGSZ 1024
#define THRESH 0.65f
#define NEGV -1.0e9f

// ---------- K0: per-pixel inverse L2 norm over channels ----------
__global__ __launch_bounds__(256) void k_invnorm(const float* __restrict__ emb,
                                                 float* __restrict__ invnorm) {
    int p = blockIdx.x * 256 + threadIdx.x;   // 0..4095
    float s = 0.f;
#pragma unroll 8
    for (int c = 0; c < CCH; ++c) {
        float v = emb[c * PIX + p];
        s = fmaf(v, v, s);
    }
    invnorm[p] = 1.0f / sqrtf(s);
}

// ---------- K1: sim[l][p] = invnorm[p] * dot(ref[l], emb[:,p]) ----------
__global__ __launch_bounds__(256) void k_sim(const float* __restrict__ emb,
                                             const float* __restrict__ ref,
                                             const float* __restrict__ invnorm,
                                             float* __restrict__ sim) {
    int p = blockIdx.x * 256 + threadIdx.x;   // pixel
    int l = blockIdx.y;                       // ref index
    const float* rl = ref + l * CCH;
    float acc = 0.f;
#pragma unroll 8
    for (int c = 0; c < CCH; ++c)
        acc = fmaf(rl[c], emb[c * PIX + p], acc);
    sim[l * PIX + p] = acc * invnorm[p];
}

// ---------- K2: per (l, gy, gx) grid cell: bilinear-upsampled 64x64 block,
// masked max+argmax (fg) and global min+argmin (bg partial) ----------
__global__ __launch_bounds__(256) void k_blocks(const float* __restrict__ sim,
                                                float* __restrict__ fgval,
                                                int* __restrict__ fgidx,
                                                float* __restrict__ bgval,
                                                int* __restrict__ bgidx) {
    const int gx = blockIdx.x, gy = blockIdx.y, l = blockIdx.z;
    const int t = threadIdx.x;

    __shared__ float patch[6][6];
    __shared__ float s_fv[256]; __shared__ int s_fi[256];
    __shared__ float s_bv[256]; __shared__ int s_bi[256];

    if (t < 36) {
        int i = t / 6, j = t % 6;
        int ry = min(max(4 * gy - 1 + i, 0), 63);
        int rx = min(max(4 * gx - 1 + j, 0), 63);
        patch[i][j] = sim[l * PIX + ry * 64 + rx];
    }
    __syncthreads();

    const int dx  = t & 63;          // output col within block
    const int dy0 = (t >> 6) * 16;   // 4 row-strips of 16

    const int x = gx * 64 + dx;
    // jax.image.resize bilinear: sample_f = (i+0.5)/16 - 0.5 = (i-7.5)/16,
    // edge handling == clamp of the sample coordinate (weights renormalize to 1).
    float tx = fminf(fmaxf((float)(x) * 0.0625f - 0.46875f, 0.f), 63.f);
    int   x0 = (int)tx;              // floor (tx >= 0)
    float wx = tx - (float)x0;       // exact multiple of 1/32
    int   x1 = min(x0 + 1, 63);
    int  lx0 = x0 - (4 * gx - 1);    // LDS col index, in [0,5]
    int  lx1 = x1 - (4 * gx - 1);
    lx1 = min(lx1, 5);
    const float owx = 1.0f - wx;

    float fbv = -FLT_MAX; int fbi = 0x7fffffff;   // fg: masked max, first idx
    float bbv =  FLT_MAX; int bbi = 0x7fffffff;   // bg: min, first idx

    for (int k = 0; k < 16; ++k) {
        int dy = dy0 + k;
        int y  = gy * 64 + dy;
        float ty = fminf(fmaxf((float)(y) * 0.0625f - 0.46875f, 0.f), 63.f);
        int   y0 = (int)ty;
        float wy = ty - (float)y0;
        int   y1 = min(y0 + 1, 63);
        int  ly0 = y0 - (4 * gy - 1);
        int  ly1 = min(y1 - (4 * gy - 1), 5);

        float v00 = patch[ly0][lx0], v01 = patch[ly0][lx1];
        float v10 = patch[ly1][lx0], v11 = patch[ly1][lx1];
        // separable lerp; exact replication when wx==0 / wy==0 (fma-safe)
        float ix0 = owx * v00 + wx * v01;
        float ix1 = owx * v10 + wx * v11;
        float val = (1.0f - wy) * ix0 + wy * ix1;

        // fg: masked value, tie -> smallest in-block flat idx (dy*64+dx)
        float m  = (val > THRESH) ? val : NEGV;
        int   fi = dy * 64 + dx;
        if (m > fbv || (m == fbv && fi < fbi)) { fbv = m; fbi = fi; }
        // bg: min, tie -> smallest global flat idx (y*1024+x)
        int   bi = y * IMGSZ + x;
        if (val < bbv || (val == bbv && bi < bbi)) { bbv = val; bbi = bi; }
    }

    s_fv[t] = fbv; s_fi[t] = fbi; s_bv[t] = bbv; s_bi[t] = bbi;
    __syncthreads();
    for (int off = 128; off > 0; off >>= 1) {
        if (t < off) {
            float v2 = s_fv[t + off]; int i2 = s_fi[t + off];
            if (v2 > s_fv[t] || (v2 == s_fv[t] && i2 < s_fi[t])) { s_fv[t] = v2; s_fi[t] = i2; }
            v2 = s_bv[t + off]; i2 = s_bi[t + off];
            if (v2 < s_bv[t] || (v2 == s_bv[t] && i2 < s_bi[t])) { s_bv[t] = v2; s_bi[t] = i2; }
        }
        __syncthreads();
    }
    if (t == 0) {
        int g = (l * NGRID + gy) * NGRID + gx;
        fgval[g] = s_fv[0]; fgidx[g] = s_fi[0];
        bgval[g] = s_bv[0]; bgidx[g] = s_bi[0];
    }
}

// ---------- K3: per l: assemble pts, stable counting sort by score desc,
// reduce bg partials; write outputs ----------
__global__ __launch_bounds__(256) void k_final(const float* __restrict__ fgval,
                                               const int* __restrict__ fgidx,
                                               const float* __restrict__ bgval,
                                               const int* __restrict__ bgidx,
                                               float* __restrict__ out) {
    const int l = blockIdx.x;
    const int t = threadIdx.x;   // grid index g = gy*16+gx

    __shared__ float sc[256];
    __shared__ float s_bv[256]; __shared__ int s_bi[256];

    float bv = fgval[l * 256 + t];
    int   bi = fgidx[l * 256 + t];
    bool valid = bv > (NEGV * 0.5f);     // best > NEG/2
    int gy = t >> 4, gx = t & 15;
    int dy = bi >> 6, dx = bi & 63;
    float xx = valid ? (float)(gx * 64 + dx) : 0.f;
    float yy = valid ? (float)(gy * 64 + dy) : 0.f;
    float ss = valid ? bv : 0.f;

    sc[t] = ss;
    s_bv[t] = bgval[l * 256 + t];
    s_bi[t] = bgidx[l * 256 + t];
    __syncthreads();

    // stable descending rank: # of entries strictly greater, or equal with lower idx
    int rank = 0;
    for (int j = 0; j < 256; ++j) {
        float o = sc[j];
        rank += (o > ss) || (o == ss && j < t);
    }
    float* p = out + (size_t)(l * 256 + rank) * 3;
    p[0] = xx; p[1] = yy; p[2] = ss;

    // bg: min across 256 partials, tie -> smallest flat idx
    for (int off = 128; off > 0; off >>= 1) {
        __syncthreads();
        if (t < off) {
            float v2 = s_bv[t + off]; int i2 = s_bi[t + off];
            if (v2 < s_bv[t] || (v2 == s_bv[t] && i2 < s_bi[t])) { s_bv[t] = v2; s_bi[t] = i2; }
        }
    }
    __syncthreads();
    if (t == 0) {
        int k = s_bi[0];
        out[(size_t)LREF * 256 * 3 + l * 2 + 0] = (float)(k % IMGSZ);  // x
        out[(size_t)LREF * 256 * 3 + l * 2 + 1] = (float)(k / IMGSZ);  // y
    }
}

extern "C" void kernel_launch(void* const* d_in, const int* in_sizes, int n_in,
                              void* d_out, int out_size, void* d_ws, size_t ws_size,
                              hipStream_t stream) {
    const float* emb = (const float*)d_in[0];   // (1,256,64,64)
    const float* ref = (const float*)d_in[1];   // (64,1,256)
    float* out = (float*)d_out;                 // 49152 (pts) + 128 (bg)

    // workspace layout (floats)
    float* ws      = (float*)d_ws;
    float* invnorm = ws;                         // 4096
    float* sim     = ws + 4096;                  // 64*4096 = 262144
    float* fgv     = sim + (size_t)LREF * PIX;   // 64*256
    int*   fgi     = (int*)(fgv + LREF * 256);
    float* bgv     = (float*)(fgi + LREF * 256);
    int*   bgi     = (int*)(bgv + LREF * 256);

    k_invnorm<<<dim3(PIX / 256), dim3(256), 0, stream>>>(emb, invnorm);
    k_sim<<<dim3(PIX / 256, LREF), dim3(256), 0, stream>>>(emb, ref, invnorm, sim);
    k_blocks<<<dim3(NGRID, NGRID, LREF), dim3(256), 0, stream>>>(sim, fgv, fgi, bgv, bgi);
    k_final<<<dim3(LREF), dim3(256), 0, stream>>>(fgv, fgi, bgv, bgi, out);
}

// Round 2
// 109.768 us; speedup vs baseline: 1.4405x; 1.4405x over previous
//
#include <hip/hip_runtime.h>
#include <float.h>
#include <math.h>

#define CCH 256       // channels
#define PIX 4096      // 64*64 feature pixels
#define LREF 64       // number of reference feats
#define NGRID 16      // grids per side
#define IMGSZ 1024
#define THRESH 0.65f
#define NEGV -1.0e9f

// ---------- K1: fused norm + sim. Each thread: one pixel, 4 l's ----------
__global__ __launch_bounds__(256) void k_sim(const float* __restrict__ emb,
                                             const float* __restrict__ ref,
                                             float* __restrict__ sim) {
    const int p  = blockIdx.x * 256 + threadIdx.x;   // pixel
    const int l0 = blockIdx.y * 4;                   // ref group
    const float* r0 = ref + (size_t)(l0 + 0) * CCH;  // wave-uniform -> s_load
    const float* r1 = ref + (size_t)(l0 + 1) * CCH;
    const float* r2 = ref + (size_t)(l0 + 2) * CCH;
    const float* r3 = ref + (size_t)(l0 + 3) * CCH;
    float a0 = 0.f, a1 = 0.f, a2 = 0.f, a3 = 0.f, nn = 0.f;
#pragma unroll 8
    for (int c = 0; c < CCH; ++c) {
        float v = emb[c * PIX + p];
        nn = fmaf(v, v, nn);
        a0 = fmaf(r0[c], v, a0);
        a1 = fmaf(r1[c], v, a1);
        a2 = fmaf(r2[c], v, a2);
        a3 = fmaf(r3[c], v, a3);
    }
    float inv = 1.0f / sqrtf(nn);
    sim[(size_t)(l0 + 0) * PIX + p] = a0 * inv;
    sim[(size_t)(l0 + 1) * PIX + p] = a1 * inv;
    sim[(size_t)(l0 + 2) * PIX + p] = a2 * inv;
    sim[(size_t)(l0 + 3) * PIX + p] = a3 * inv;
}

// ---------- K2: per (l, gy, gx) grid cell ----------
// thread t: column dx = t&63, row-strip s = t>>6 (16 output rows).
// Only source rows s, s+1, s+2 are touched by this strip; the x-lerp is
// hoisted so the inner loop is a single lerp with compile-time wy.
__global__ __launch_bounds__(256) void k_blocks(const float* __restrict__ sim,
                                                float* __restrict__ fgval,
                                                int* __restrict__ fgidx,
                                                float* __restrict__ bgval,
                                                int* __restrict__ bgidx) {
    const int gx = blockIdx.x, gy = blockIdx.y, l = blockIdx.z;
    const int t = threadIdx.x;

    __shared__ float patch[6][6];
    __shared__ float r_fv[4]; __shared__ int r_fi[4];
    __shared__ float r_bv[4]; __shared__ int r_bi[4];

    if (t < 36) {
        int i = t / 6, j = t % 6;
        int ry = min(max(4 * gy - 1 + i, 0), 63);
        int rx = min(max(4 * gx - 1 + j, 0), 63);
        patch[i][j] = sim[(size_t)l * PIX + ry * 64 + rx];
    }
    __syncthreads();

    const int dx = t & 63;
    const int s  = t >> 6;           // wave-uniform (wave = 64 lanes)

    const int x = gx * 64 + dx;
    // sample_f = (x+0.5)/16 - 0.5, clamped (== jax.image.resize edge handling)
    float tx = fminf(fmaxf((float)x * 0.0625f - 0.46875f, 0.f), 63.f);
    int   x0 = (int)tx;
    float wx = tx - (float)x0;
    int   x1 = min(x0 + 1, 63);
    int  lx0 = x0 - (4 * gx - 1);
    int  lx1 = min(x1 - (4 * gx - 1), 5);
    const float owx = 1.0f - wx;

    // hoisted horizontal lerps for the 3 source rows this strip touches
    float hA = owx * patch[s    ][lx0] + wx * patch[s    ][lx1];
    float hB = owx * patch[s + 1][lx0] + wx * patch[s + 1][lx1];
    float hC = owx * patch[s + 2][lx0] + wx * patch[s + 2][lx1];

    const bool edgeB = (gy == 0  && s == 0);   // wy clamps to 0 -> use row 0 (=hB)
    const bool edgeT = (gy == 15 && s == 3);   // wy clamps to 0 at row 63 (=hB)

    float fbv = THRESH; int fbk = -1;    // fg: strict >, so >THRESH fused in
    float bbv = FLT_MAX; int bbk = 0;    // bg: min

#pragma unroll
    for (int k = 0; k < 16; ++k) {
        // k<8: y0 = 4gy+s-1 (pair hA,hB), wy = 0.53125 + k/16
        // k>=8: y0 = 4gy+s   (pair hB,hC), wy = 0.03125 + (k-8)/16
        float wy = (k < 8) ? (0.53125f + 0.0625f * (float)k)
                           : (0.03125f + 0.0625f * (float)(k - 8));
        if (k < 8)  { if (edgeB) wy = 1.0f; }   // clamped: val == row0 == hB
        else        { if (edgeT) wy = 0.0f; }   // clamped: val == row63 == hB
        float h0 = (k < 8) ? hA : hB;
        float h1 = (k < 8) ? hB : hC;
        float val = (1.0f - wy) * h0 + wy * h1;
        // indices are ascending in k per thread -> strict compare keeps first
        if (val > fbv) { fbv = val; fbk = k; }
        if (val < bbv) { bbv = val; bbk = k; }
    }

    // materialize (value, first-flat-index) pairs
    float rv = (fbk >= 0) ? fbv : NEGV;
    int   ri = (fbk >= 0) ? (1024 * s + 64 * fbk + dx) : 0x7fffffff; // in-block idx
    float bv = bbv;
    int   bj = ((gy * 64 + 16 * s + bbk) << 10) + gx * 64 + dx;      // global idx

    // wave-level reduction (64 lanes), tie -> lowest index
#pragma unroll
    for (int off = 32; off > 0; off >>= 1) {
        float v2 = __shfl_xor(rv, off); int i2 = __shfl_xor(ri, off);
        if (v2 > rv || (v2 == rv && i2 < ri)) { rv = v2; ri = i2; }
        float w2 = __shfl_xor(bv, off); int j2 = __shfl_xor(bj, off);
        if (w2 < bv || (w2 == bv && j2 < bj)) { bv = w2; bj = j2; }
    }
    if ((t & 63) == 0) {
        int w = t >> 6;
        r_fv[w] = rv; r_fi[w] = ri; r_bv[w] = bv; r_bi[w] = bj;
    }
    __syncthreads();
    if (t == 0) {
#pragma unroll
        for (int w = 1; w < 4; ++w) {
            float v2 = r_fv[w]; int i2 = r_fi[w];
            if (v2 > rv || (v2 == rv && i2 < ri)) { rv = v2; ri = i2; }
            v2 = r_bv[w]; i2 = r_bi[w];
            if (v2 < bv || (v2 == bv && i2 < bj)) { bv = v2; bj = i2; }
        }
        int g = (l * NGRID + gy) * NGRID + gx;
        fgval[g] = rv; fgidx[g] = ri; bgval[g] = bv; bgidx[g] = bj;
    }
}

// ---------- K3: per l: assemble pts, stable rank by score desc, bg reduce ----------
__global__ __launch_bounds__(256) void k_final(const float* __restrict__ fgval,
                                               const int* __restrict__ fgidx,
                                               const float* __restrict__ bgval,
                                               const int* __restrict__ bgidx,
                                               float* __restrict__ out) {
    const int l = blockIdx.x;
    const int t = threadIdx.x;   // grid index g = gy*16+gx

    __shared__ float sc[256];
    __shared__ float r_bv[4]; __shared__ int r_bi[4];

    float bvf = fgval[l * 256 + t];
    int   bif = fgidx[l * 256 + t];
    bool valid = bvf > (NEGV * 0.5f);
    int gy = t >> 4, gx = t & 15;
    int dy = (bif >> 6) & 63, dx = bif & 63;
    float xx = valid ? (float)(gx * 64 + dx) : 0.f;
    float yy = valid ? (float)(gy * 64 + dy) : 0.f;
    float ss = valid ? bvf : 0.f;

    sc[t] = ss;
    float bv = bgval[l * 256 + t];
    int   bj = bgidx[l * 256 + t];
    __syncthreads();

    // stable descending rank
    int rank = 0;
    for (int j = 0; j < 256; ++j) {
        float o = sc[j];
        rank += (o > ss) || (o == ss && j < t);
    }
    float* p = out + (size_t)(l * 256 + rank) * 3;
    p[0] = xx; p[1] = yy; p[2] = ss;

    // bg: min across 256 partials, tie -> smallest flat idx
#pragma unroll
    for (int off = 32; off > 0; off >>= 1) {
        float w2 = __shfl_xor(bv, off); int j2 = __shfl_xor(bj, off);
        if (w2 < bv || (w2 == bv && j2 < bj)) { bv = w2; bj = j2; }
    }
    if ((t & 63) == 0) { r_bv[t >> 6] = bv; r_bi[t >> 6] = bj; }
    __syncthreads();
    if (t == 0) {
#pragma unroll
        for (int w = 1; w < 4; ++w) {
            float w2 = r_bv[w]; int j2 = r_bi[w];
            if (w2 < bv || (w2 == bv && j2 < bj)) { bv = w2; bj = j2; }
        }
        out[(size_t)LREF * 256 * 3 + l * 2 + 0] = (float)(bj & (IMGSZ - 1));  // x
        out[(size_t)LREF * 256 * 3 + l * 2 + 1] = (float)(bj >> 10);          // y
    }
}

extern "C" void kernel_launch(void* const* d_in, const int* in_sizes, int n_in,
                              void* d_out, int out_size, void* d_ws, size_t ws_size,
                              hipStream_t stream) {
    const float* emb = (const float*)d_in[0];   // (1,256,64,64)
    const float* ref = (const float*)d_in[1];   // (64,1,256)
    float* out = (float*)d_out;                 // 49152 (pts) + 128 (bg)

    float* ws  = (float*)d_ws;
    float* sim = ws;                             // 64*4096
    float* fgv = sim + (size_t)LREF * PIX;       // 64*256
    int*   fgi = (int*)(fgv + LREF * 256);
    float* bgv = (float*)(fgi + LREF * 256);
    int*   bgi = (int*)(bgv + LREF * 256);

    k_sim<<<dim3(PIX / 256, LREF / 4), dim3(256), 0, stream>>>(emb, ref, sim);
    k_blocks<<<dim3(NGRID, NGRID, LREF), dim3(256), 0, stream>>>(sim, fgv, fgi, bgv, bgi);
    k_final<<<dim3(LREF), dim3(256), 0, stream>>>(fgv, fgi, bgv, bgi, out);
}

// Round 3
// 93.671 us; speedup vs baseline: 1.6881x; 1.1719x over previous
//
#include <hip/hip_runtime.h>
#include <float.h>
#include <math.h>

#define CCH 256       // channels
#define PIX 4096      // 64*64 feature pixels
#define LREF 64       // number of reference feats
#define IMGSZ 1024
#define THRESH 0.65f
#define NEGV -1.0e9f

// monotone bijection fp32 -> u32 (order-preserving, no NaNs in data)
__device__ __forceinline__ unsigned mono32(float v) {
    unsigned u = __float_as_uint(v);
    return u ^ ((unsigned)((int)u >> 31) | 0x80000000u);
}
__device__ __forceinline__ float unmono32(unsigned m) {
    unsigned u = (m & 0x80000000u) ? (m ^ 0x80000000u) : ~m;
    return __uint_as_float(u);
}
// lerp that is EXACT at w==0 (-> a) and w==1 (-> b): fmaf(-0,a,a)=a, fmaf(-1,a,a)=0
__device__ __forceinline__ float lrp(float a, float b, float w) {
    return fmaf(w, b, fmaf(-w, a, a));
}

// ---------- K1: fused norm + sim. Each thread: one pixel, 4 l's ----------
__global__ __launch_bounds__(256) void k_sim(const float* __restrict__ emb,
                                             const float* __restrict__ ref,
                                             float* __restrict__ sim) {
    const int p  = blockIdx.x * 256 + threadIdx.x;   // pixel
    const int l0 = blockIdx.y * 4;                   // ref group
    const float* r0 = ref + (size_t)(l0 + 0) * CCH;  // wave-uniform -> s_load
    const float* r1 = ref + (size_t)(l0 + 1) * CCH;
    const float* r2 = ref + (size_t)(l0 + 2) * CCH;
    const float* r3 = ref + (size_t)(l0 + 3) * CCH;
    float a0 = 0.f, a1 = 0.f, a2 = 0.f, a3 = 0.f, nn = 0.f;
#pragma unroll 8
    for (int c = 0; c < CCH; ++c) {
        float v = emb[c * PIX + p];
        nn = fmaf(v, v, nn);
        a0 = fmaf(r0[c], v, a0);
        a1 = fmaf(r1[c], v, a1);
        a2 = fmaf(r2[c], v, a2);
        a3 = fmaf(r3[c], v, a3);
    }
    float inv = 1.0f / sqrtf(nn);
    sim[(size_t)(l0 + 0) * PIX + p] = a0 * inv;
    sim[(size_t)(l0 + 1) * PIX + p] = a1 * inv;
    sim[(size_t)(l0 + 2) * PIX + p] = a2 * inv;
    sim[(size_t)(l0 + 3) * PIX + p] = a3 * inv;
}

// ---------- K2: one block per (l, gy, cell-pair {2q, 2q+1}) ----------
// thread t: column dx = t&63 (same wx in both cells: x differs by 64 = 4 src
// cols exactly), strip s = t>>6 (16 output rows using src rows s,s+1,s+2).
// Loop tracks only min/max; indices recovered by equality scans (exact);
// fg reduction skipped via ballot when no value exceeds THRESH.
__global__ __launch_bounds__(256) void k_blocks(const float* __restrict__ sim,
                                                float* __restrict__ fgval,
                                                int* __restrict__ fgidx,
                                                unsigned long long* __restrict__ bgkey) {
    const int gq = blockIdx.x;   // 0..7  -> cells gx=2gq, 2gq+1
    const int gy = blockIdx.y;   // 0..15
    const int l  = blockIdx.z;   // 0..63
    const int t  = threadIdx.x;

    __shared__ float patch[6][10];       // src rows 4gy-1..4gy+4, cols 8gq-1..8gq+8
    __shared__ unsigned long long s_fgA[4], s_fgB[4], s_bg[4];

    if (t < 60) {
        int i = t / 10, j = t % 10;
        int ry = min(max(4 * gy - 1 + i, 0), 63);
        int rx = min(max(8 * gq - 1 + j, 0), 63);
        patch[i][j] = sim[(size_t)l * PIX + ry * 64 + rx];
    }
    __syncthreads();

    const int dx = t & 63;
    const int s  = t >> 6;               // wave-uniform
    const int xA = gq * 128 + dx;
    const int xB = xA + 64;
    const int jb = 8 * gq - 1;           // lds col base (src col)

    // sample_f = (x+0.5)/16 - 0.5, clamped (== jax.image.resize edge handling)
    float txA = fminf(fmaxf((float)xA * 0.0625f - 0.46875f, 0.f), 63.f);
    int x0A = (int)txA; float wxA = txA - (float)x0A; int x1A = min(x0A + 1, 63);
    int jA0 = x0A - jb, jA1 = x1A - jb;
    float txB = fminf(fmaxf((float)xB * 0.0625f - 0.46875f, 0.f), 63.f);
    int x0B = (int)txB; float wxB = txB - (float)x0B; int x1B = min(x0B + 1, 63);
    int jB0 = x0B - jb, jB1 = x1B - jb;

    // hoisted horizontal lerps for the 3 src rows this strip touches
    float hA0 = lrp(patch[s    ][jA0], patch[s    ][jA1], wxA);
    float hA1 = lrp(patch[s + 1][jA0], patch[s + 1][jA1], wxA);
    float hA2 = lrp(patch[s + 2][jA0], patch[s + 2][jA1], wxA);
    float hB0 = lrp(patch[s    ][jB0], patch[s    ][jB1], wxB);
    float hB1 = lrp(patch[s + 1][jB0], patch[s + 1][jB1], wxB);
    float hB2 = lrp(patch[s + 2][jB0], patch[s + 2][jB1], wxB);

    const bool edgeB = (gy == 0  && s == 0);   // rows clamp -> val == src row 0
    const bool edgeT = (gy == 15 && s == 3);   // rows clamp -> val == src row 63

    float vA[16], vB[16];
    float fmA = THRESH, fmB = THRESH;    // fg: any val strictly > THRESH
    float bmA = FLT_MAX, bmB = FLT_MAX;  // bg: min
#pragma unroll
    for (int k = 0; k < 16; ++k) {
        // k<8: src rows (s, s+1), wy = 0.53125 + k/16
        // k>=8: src rows (s+1, s+2), wy = 0.03125 + (k-8)/16
        float wy = (k < 8) ? (0.53125f + 0.0625f * (float)k)
                           : (0.03125f + 0.0625f * (float)(k - 8));
        if (k < 8)  { if (edgeB) wy = 1.0f; }   // exact: val == h1 == src row 0
        else        { if (edgeT) wy = 0.0f; }   // exact: val == h0 == src row 63
        float a0 = (k < 8) ? hA0 : hA1, a1 = (k < 8) ? hA1 : hA2;
        float b0 = (k < 8) ? hB0 : hB1, b1 = (k < 8) ? hB1 : hB2;
        vA[k] = lrp(a0, a1, wy);
        vB[k] = lrp(b0, b1, wy);
        fmA = fmaxf(fmA, vA[k]); bmA = fminf(bmA, vA[k]);
        fmB = fmaxf(fmB, vB[k]); bmB = fminf(bmB, vB[k]);
    }

    // ---- bg: first-k recovery (reverse equality scan; min/max are exact) ----
    int bkA = 0, bkB = 0;
#pragma unroll
    for (int k = 15; k >= 0; --k) {
        if (vA[k] == bmA) bkA = k;
        if (vB[k] == bmB) bkB = k;
    }
    const int ybase = gy * 64 + s * 16;
    unsigned long long keyA =
        ((unsigned long long)mono32(bmA) << 32) | (unsigned)(((ybase + bkA) << 10) + xA);
    unsigned long long keyB =
        ((unsigned long long)mono32(bmB) << 32) | (unsigned)(((ybase + bkB) << 10) + xB);
    unsigned long long bg = keyA < keyB ? keyA : keyB;   // global idx -> exact tie
#pragma unroll
    for (int off = 32; off > 0; off >>= 1) {
        unsigned long long o = __shfl_xor(bg, off);
        if (o < bg) bg = o;
    }

    // ---- fg: rare path, whole reduction skipped when wave has no candidate ----
    bool fA = fmA > THRESH, fB = fmB > THRESH;
    unsigned long long kA = 0ULL, kB = 0ULL;
    if (__ballot(fA)) {
        int fk = 0;
#pragma unroll
        for (int k = 15; k >= 0; --k) if (vA[k] == fmA) fk = k;
        int fi = (s * 16 + fk) * 64 + dx;            // in-block flat idx
        kA = fA ? (((unsigned long long)mono32(fmA) << 32) | (unsigned)(4095 - fi)) : 0ULL;
#pragma unroll
        for (int off = 32; off > 0; off >>= 1) {
            unsigned long long o = __shfl_xor(kA, off);
            if (o > kA) kA = o;                       // max val, tie -> min fi
        }
    }
    if (__ballot(fB)) {
        int fk = 0;
#pragma unroll
        for (int k = 15; k >= 0; --k) if (vB[k] == fmB) fk = k;
        int fi = (s * 16 + fk) * 64 + dx;
        kB = fB ? (((unsigned long long)mono32(fmB) << 32) | (unsigned)(4095 - fi)) : 0ULL;
#pragma unroll
        for (int off = 32; off > 0; off >>= 1) {
            unsigned long long o = __shfl_xor(kB, off);
            if (o > kB) kB = o;
        }
    }

    if ((t & 63) == 0) { int w = t >> 6; s_fgA[w] = kA; s_fgB[w] = kB; s_bg[w] = bg; }
    __syncthreads();
    if (t == 0) {
        unsigned long long a = s_fgA[0], b = s_fgB[0], g = s_bg[0];
#pragma unroll
        for (int w = 1; w < 4; ++w) {
            if (s_fgA[w] > a) a = s_fgA[w];
            if (s_fgB[w] > b) b = s_fgB[w];
            if (s_bg[w]  < g) g = s_bg[w];
        }
        int cell = (l * 16 + gy) * 16 + 2 * gq;
        fgval[cell]     = a ? unmono32((unsigned)(a >> 32)) : NEGV;
        fgidx[cell]     = a ? (4095 - (int)(a & 0xffffffffULL)) : 0x7fffffff;
        fgval[cell + 1] = b ? unmono32((unsigned)(b >> 32)) : NEGV;
        fgidx[cell + 1] = b ? (4095 - (int)(b & 0xffffffffULL)) : 0x7fffffff;
        bgkey[cell] = g; bgkey[cell + 1] = g;   // idempotent under k_final's min
    }
}

// ---------- K3: per l: assemble pts, stable rank by score desc, bg key-min ----------
__global__ __launch_bounds__(256) void k_final(const float* __restrict__ fgval,
                                               const int* __restrict__ fgidx,
                                               const unsigned long long* __restrict__ bgkey,
                                               float* __restrict__ out) {
    const int l = blockIdx.x;
    const int t = threadIdx.x;   // grid cell g = gy*16+gx

    __shared__ float sc[256];
    __shared__ unsigned long long s_bg[4];

    float bvf = fgval[l * 256 + t];
    int   bif = fgidx[l * 256 + t];
    bool valid = bvf > (NEGV * 0.5f);
    int gy = t >> 4, gx = t & 15;
    int dy = (bif >> 6) & 63, dx = bif & 63;
    float xx = valid ? (float)(gx * 64 + dx) : 0.f;
    float yy = valid ? (float)(gy * 64 + dy) : 0.f;
    float ss = valid ? bvf : 0.f;

    sc[t] = ss;
    unsigned long long bg = bgkey[l * 256 + t];
    __syncthreads();

    // stable descending rank
    int rank = 0;
    for (int j = 0; j < 256; ++j) {
        float o = sc[j];
        rank += (o > ss) || (o == ss && j < t);
    }
    float* p = out + (size_t)(l * 256 + rank) * 3;
    p[0] = xx; p[1] = yy; p[2] = ss;

    // bg: min key across 256 cells (value, then smallest global flat idx)
#pragma unroll
    for (int off = 32; off > 0; off >>= 1) {
        unsigned long long o = __shfl_xor(bg, off);
        if (o < bg) bg = o;
    }
    if ((t & 63) == 0) s_bg[t >> 6] = bg;
    __syncthreads();
    if (t == 0) {
#pragma unroll
        for (int w = 1; w < 4; ++w) if (s_bg[w] < bg) bg = s_bg[w];
        unsigned idx = (unsigned)(bg & 0xffffffffULL);
        out[(size_t)LREF * 256 * 3 + l * 2 + 0] = (float)(idx & (IMGSZ - 1));  // x
        out[(size_t)LREF * 256 * 3 + l * 2 + 1] = (float)(idx >> 10);          // y
    }
}

extern "C" void kernel_launch(void* const* d_in, const int* in_sizes, int n_in,
                              void* d_out, int out_size, void* d_ws, size_t ws_size,
                              hipStream_t stream) {
    const float* emb = (const float*)d_in[0];   // (1,256,64,64)
    const float* ref = (const float*)d_in[1];   // (64,1,256)
    float* out = (float*)d_out;                 // 49152 (pts) + 128 (bg)

    float* ws  = (float*)d_ws;
    float* sim = ws;                                          // 64*4096 f32 (1 MB)
    unsigned long long* bgk = (unsigned long long*)(sim + (size_t)LREF * PIX);  // 16384 u64 (8B-aligned)
    float* fgv = (float*)(bgk + LREF * 256);                  // 16384 f32
    int*   fgi = (int*)(fgv + LREF * 256);                    // 16384 i32

    k_sim<<<dim3(PIX / 256, LREF / 4), dim3(256), 0, stream>>>(emb, ref, sim);
    k_blocks<<<dim3(8, 16, LREF), dim3(256), 0, stream>>>(sim, fgv, fgi, bgk);
    k_final<<<dim3(LREF), dim3(256), 0, stream>>>(fgv, fgi, bgk, out);
}